// Round 19
// baseline (1194.203 us; speedup 1.0000x reference)
//
#include <hip/hip_runtime.h>
#include <hip/hip_bf16.h>
#include <math.h>

#define B_ 64
#define HB_ 32
#define L_ 57
#define D_ 512
#define H_ 8
#define DK_ 64
#define NC_ 2048

// ---------------- weight transpose: w[cout][cin][k] -> wT[cin*K + k][cout]
__global__ __launch_bounds__(256) void wtrans_k(const float* __restrict__ w,
                                                float* __restrict__ wT,
                                                int CINK, int COUT)
{
  int idx = blockIdx.x * 256 + threadIdx.x;
  if (idx >= CINK * COUT) return;
  int r = idx / COUT, c = idx - r * COUT;
  wT[idx] = w[(size_t)c * CINK + r];
}

// ---------------- padded weight transpose (zero rows >= CINK)
__global__ __launch_bounds__(256) void wtransp_k(const float* __restrict__ w,
                                                 float* __restrict__ wT,
                                                 int CINK, int CINK_PAD, int COUT)
{
  int idx = blockIdx.x * 256 + threadIdx.x;
  if (idx >= CINK_PAD * COUT) return;
  int r = idx / COUT, c = idx - r * COUT;
  wT[idx] = (r < CINK) ? w[(size_t)c * CINK + r] : 0.f;
}

// ---------------- qkv weight prep
__global__ __launch_bounds__(256) void wqkvprep_k(
    const float* __restrict__ wq, const float* __restrict__ wk,
    const float* __restrict__ wv, float* __restrict__ wqkvT)
{
  int idx = blockIdx.x * 256 + threadIdx.x;   // 3*512*512 = 786432
  if (idx >= 786432) return;
  int set = idx >> 18;
  int h   = (idx >> 15) & 7;
  int d   = (idx >> 6) & 511;
  int kd  = idx & 63;
  const float* W = (set == 0 ? wq : (set == 1 ? wk : wv));
  float v = W[((size_t)h * 512 + d) * 64 + kd];
  wqkvT[(size_t)d * 1536 + set * 512 + h * 64 + kd] = v;
}

// ---------------- conv1d TT=64 (fallback path)
template<int CIN, int K, int S, int COUT, int CC>
__global__ __launch_bounds__(256, 4) void conv1d_k(
    const float* __restrict__ x, const float* __restrict__ wT,
    const float* __restrict__ bias, float* __restrict__ y,
    int Tin, int Tout)
{
  constexpr int TT = 64;
  constexpr int SPAN = S * TT + K - S;
  __shared__ float xs[CC * SPAN];
  const int b   = blockIdx.z;
  const int cbk = blockIdx.y;
  const int t0  = blockIdx.x * TT;
  const int tid = threadIdx.x;
  const int lane_t = tid & 63;
  const int g = tid >> 6;
  const int coutBase = __builtin_amdgcn_readfirstlane(cbk * 64 + g * 16);
  const int t = t0 + lane_t;
  float acc[16];
#pragma unroll
  for (int j = 0; j < 16; ++j) acc[j] = 0.f;
  const float* xb = x + (size_t)b * CIN * Tin;
  const int col0 = t0 * S;

  for (int c0 = 0; c0 < CIN; c0 += CC) {
    __syncthreads();
    for (int e = tid; e < CC * SPAN; e += 256) {
      int cc = e / SPAN, col = e - cc * SPAN;
      int ti = col0 + col;
      xs[e] = (ti < Tin) ? xb[(size_t)(c0 + cc) * Tin + ti] : 0.f;
    }
    __syncthreads();

    const float* wchunk = wT + ((size_t)c0 * K) * COUT + coutBase;
    for (int cc = 0; cc < CC; ++cc) {
#pragma unroll
      for (int kk = 0; kk < K; ++kk) {
        const float* wrow = wchunk + (size_t)(cc * K + kk) * COUT;
        float wv[16];
#pragma unroll
        for (int j = 0; j < 16; ++j) wv[j] = wrow[j];
        float xv = xs[cc * SPAN + lane_t * S + kk];
#pragma unroll
        for (int j = 0; j < 16; ++j) acc[j] += xv * wv[j];
      }
    }
  }
  if (t < Tout) {
#pragma unroll
    for (int j = 0; j < 16; ++j) {
      int co = coutBase + j;
      y[((size_t)b * COUT + co) * Tout + t] = acc[j] + bias[co];
    }
  }
}

// ---------------- conv1d TT=128: 2 t/lane -> 32 FMA per weight-row stall
template<int CIN, int K, int S, int COUT, int CC>
__global__ __launch_bounds__(256, 4) void conv1dw_k(
    const float* __restrict__ x, const float* __restrict__ wT,
    const float* __restrict__ bias, float* __restrict__ y,
    int Tin, int Tout)
{
  constexpr int TT = 128;
  constexpr int SPAN = S * TT + K - S;
  __shared__ float xs[CC * SPAN];
  const int b   = blockIdx.z;
  const int cbk = blockIdx.y;
  const int t0  = blockIdx.x * TT;
  const int tid = threadIdx.x;
  const int lane_t = tid & 63;
  const int g = tid >> 6;
  const int coutBase = __builtin_amdgcn_readfirstlane(cbk * 64 + g * 16);
  float acc0[16], acc1[16];
#pragma unroll
  for (int j = 0; j < 16; ++j) { acc0[j] = 0.f; acc1[j] = 0.f; }
  const float* xb = x + (size_t)b * CIN * Tin;
  const int col0 = t0 * S;

  for (int c0 = 0; c0 < CIN; c0 += CC) {
    __syncthreads();
    for (int e = tid; e < CC * SPAN; e += 256) {
      int cc = e / SPAN, col = e - cc * SPAN;
      int ti = col0 + col;
      xs[e] = (ti < Tin) ? xb[(size_t)(c0 + cc) * Tin + ti] : 0.f;
    }
    __syncthreads();

    const float* wchunk = wT + ((size_t)c0 * K) * COUT + coutBase;
    for (int cc = 0; cc < CC; ++cc) {
#pragma unroll
      for (int kk = 0; kk < K; ++kk) {
        const float* wrow = wchunk + (size_t)(cc * K + kk) * COUT;
        float wv[16];
#pragma unroll
        for (int j = 0; j < 16; ++j) wv[j] = wrow[j];
        float xv0 = xs[cc * SPAN + lane_t * S + kk];
        float xv1 = xs[cc * SPAN + (lane_t + 64) * S + kk];
#pragma unroll
        for (int j = 0; j < 16; ++j) {
          acc0[j] += xv0 * wv[j];
          acc1[j] += xv1 * wv[j];
        }
      }
    }
  }
  const int t_a = t0 + lane_t, t_b = t0 + 64 + lane_t;
#pragma unroll
  for (int j = 0; j < 16; ++j) {
    int co = coutBase + j;
    float bv = bias[co];
    float* yr = y + ((size_t)b * COUT + co) * Tout;
    if (t_a < Tout) yr[t_a] = acc0[j] + bv;
    if (t_b < Tout) yr[t_b] = acc1[j] + bv;
  }
}

// ---------------- conv1 TT=128 2-way K-split: cins ks*56+[0,56), zero-guarded
// (wT padded to 112 cins). Partial output, no bias.
__global__ __launch_bounds__(256, 4) void conv1ksw_k(
    const float* __restrict__ x, const float* __restrict__ wT,
    float* __restrict__ p, int ksStrideP)
{
  constexpr int K = 10, S = 3, COUT = 64, CC = 14, TT = 128;
  constexpr int SPAN = S * TT + K - S;   // 391
  constexpr int TIN = 5500, TOUT = 1831, CINTOT = 105;
  __shared__ float xs[CC * SPAN];
  const int b  = blockIdx.z;
  const int ks = blockIdx.y;
  const int t0 = blockIdx.x * TT;
  const int tid = threadIdx.x;
  const int lane_t = tid & 63;
  const int g = tid >> 6;
  const int coutBase = __builtin_amdgcn_readfirstlane(g * 16);
  float acc0[16], acc1[16];
#pragma unroll
  for (int j = 0; j < 16; ++j) { acc0[j] = 0.f; acc1[j] = 0.f; }
  const float* xb = x + (size_t)b * CINTOT * TIN;
  const int col0 = t0 * S;

#pragma unroll
  for (int c0i = 0; c0i < 4; ++c0i) {
    const int cin0 = ks * 56 + c0i * CC;
    __syncthreads();
    for (int e = tid; e < CC * SPAN; e += 256) {
      int cc = e / SPAN, col = e - cc * SPAN;
      int gci = cin0 + cc;
      int ti = col0 + col;
      xs[e] = (ti < TIN && gci < CINTOT) ? xb[(size_t)gci * TIN + ti] : 0.f;
    }
    __syncthreads();

    const float* wchunk = wT + ((size_t)cin0 * K) * COUT + coutBase;
    for (int cc = 0; cc < CC; ++cc) {
#pragma unroll
      for (int kk = 0; kk < K; ++kk) {
        const float* wrow = wchunk + (size_t)(cc * K + kk) * COUT;
        float wv[16];
#pragma unroll
        for (int j = 0; j < 16; ++j) wv[j] = wrow[j];
        float xv0 = xs[cc * SPAN + lane_t * S + kk];
        float xv1 = xs[cc * SPAN + (lane_t + 64) * S + kk];
#pragma unroll
        for (int j = 0; j < 16; ++j) {
          acc0[j] += xv0 * wv[j];
          acc1[j] += xv1 * wv[j];
        }
      }
    }
  }
  const int t_a = t0 + lane_t, t_b = t0 + 64 + lane_t;
#pragma unroll
  for (int j = 0; j < 16; ++j) {
    int co = coutBase + j;
    float* pr = p + (size_t)ks * ksStrideP + ((size_t)b * COUT + co) * TOUT;
    if (t_a < TOUT) pr[t_a] = acc0[j];
    if (t_b < TOUT) pr[t_b] = acc1[j];
  }
}

// ---------------- K-split conv TT=64 (fallback conv5)
template<int CINC, int K, int S, int COUT, int CC, int KS>
__global__ __launch_bounds__(256, 4) void convks_k(
    const float* __restrict__ x, const float* __restrict__ wT,
    float* __restrict__ p, int Tin, int Tout, int bStrideX, int ksStrideP)
{
  constexpr int TT = 64;
  constexpr int SPAN = S * TT + K - S;
  __shared__ float xs[CC * SPAN];
  const int b   = blockIdx.z;
  const int cbk = blockIdx.y & 7;
  const int ks  = blockIdx.y >> 3;
  const int t0  = blockIdx.x * TT;
  const int tid = threadIdx.x;
  const int lane_t = tid & 63;
  const int g = tid >> 6;
  const int coutBase = __builtin_amdgcn_readfirstlane(cbk * 64 + g * 16);
  const int t = t0 + lane_t;
  float acc[16];
#pragma unroll
  for (int j = 0; j < 16; ++j) acc[j] = 0.f;
  const float* xb = x + (size_t)b * bStrideX + (size_t)ks * CINC * Tin;
  const float* wbase = wT + ((size_t)ks * CINC * K) * COUT;
  const int col0 = t0 * S;

  for (int c0 = 0; c0 < CINC; c0 += CC) {
    __syncthreads();
    for (int e = tid; e < CC * SPAN; e += 256) {
      int cc = e / SPAN, col = e - cc * SPAN;
      int ti = col0 + col;
      xs[e] = (ti < Tin) ? xb[(size_t)(c0 + cc) * Tin + ti] : 0.f;
    }
    __syncthreads();

    const float* wchunk = wbase + ((size_t)c0 * K) * COUT + coutBase;
    for (int cc = 0; cc < CC; ++cc) {
#pragma unroll
      for (int kk = 0; kk < K; ++kk) {
        const float* wrow = wchunk + (size_t)(cc * K + kk) * COUT;
        float wv[16];
#pragma unroll
        for (int j = 0; j < 16; ++j) wv[j] = wrow[j];
        float xv = xs[cc * SPAN + lane_t * S + kk];
#pragma unroll
        for (int j = 0; j < 16; ++j) acc[j] += xv * wv[j];
      }
    }
  }
  if (t < Tout) {
#pragma unroll
    for (int j = 0; j < 16; ++j) {
      int co = coutBase + j;
      p[(size_t)ks * ksStrideP + ((size_t)b * COUT + co) * Tout + t] = acc[j];
    }
  }
}

// ---------------- K-split conv TT=128 (full-batch conv5)
template<int CINC, int K, int S, int COUT, int CC, int KS>
__global__ __launch_bounds__(256, 4) void convksw_k(
    const float* __restrict__ x, const float* __restrict__ wT,
    float* __restrict__ p, int Tin, int Tout, int bStrideX, int ksStrideP)
{
  constexpr int TT = 128;
  constexpr int SPAN = S * TT + K - S;
  __shared__ float xs[CC * SPAN];
  const int b   = blockIdx.z;
  const int cbk = blockIdx.y & 7;
  const int ks  = blockIdx.y >> 3;
  const int t0  = blockIdx.x * TT;
  const int tid = threadIdx.x;
  const int lane_t = tid & 63;
  const int g = tid >> 6;
  const int coutBase = __builtin_amdgcn_readfirstlane(cbk * 64 + g * 16);
  float acc0[16], acc1[16];
#pragma unroll
  for (int j = 0; j < 16; ++j) { acc0[j] = 0.f; acc1[j] = 0.f; }
  const float* xb = x + (size_t)b * bStrideX + (size_t)ks * CINC * Tin;
  const float* wbase = wT + ((size_t)ks * CINC * K) * COUT;
  const int col0 = t0 * S;

  for (int c0 = 0; c0 < CINC; c0 += CC) {
    __syncthreads();
    for (int e = tid; e < CC * SPAN; e += 256) {
      int cc = e / SPAN, col = e - cc * SPAN;
      int ti = col0 + col;
      xs[e] = (ti < Tin) ? xb[(size_t)(c0 + cc) * Tin + ti] : 0.f;
    }
    __syncthreads();

    const float* wchunk = wbase + ((size_t)c0 * K) * COUT + coutBase;
    for (int cc = 0; cc < CC; ++cc) {
#pragma unroll
      for (int kk = 0; kk < K; ++kk) {
        const float* wrow = wchunk + (size_t)(cc * K + kk) * COUT;
        float wv[16];
#pragma unroll
        for (int j = 0; j < 16; ++j) wv[j] = wrow[j];
        float xv0 = xs[cc * SPAN + lane_t * S + kk];
        float xv1 = xs[cc * SPAN + (lane_t + 64) * S + kk];
#pragma unroll
        for (int j = 0; j < 16; ++j) {
          acc0[j] += xv0 * wv[j];
          acc1[j] += xv1 * wv[j];
        }
      }
    }
  }
  const int t_a = t0 + lane_t, t_b = t0 + 64 + lane_t;
#pragma unroll
  for (int j = 0; j < 16; ++j) {
    int co = coutBase + j;
    float* pr = p + (size_t)ks * ksStrideP + ((size_t)b * COUT + co) * Tout;
    if (t_a < Tout) pr[t_a] = acc0[j];
    if (t_b < Tout) pr[t_b] = acc1[j];
  }
}

// ---------------- conv6 with fused conv5-reduce
__global__ __launch_bounds__(256, 4) void convks6f_k(
    const float* __restrict__ pin, const float* __restrict__ wT,
    const float* __restrict__ b5, float* __restrict__ p,
    int p1Off, int ksStrideP)
{
  constexpr int CINC = 128, K = 2, S = 2, COUT = 512, CC = 32, TT = 64;
  constexpr int SPAN = S * TT + K - S;   // 128
  constexpr int TIN = 114;
  __shared__ float xs[CC * SPAN];
  const int b   = blockIdx.z;
  const int cbk = blockIdx.y & 7;
  const int ks  = blockIdx.y >> 3;
  const int t0  = blockIdx.x * TT;
  const int tid = threadIdx.x;
  const int lane_t = tid & 63;
  const int g = tid >> 6;
  const int coutBase = __builtin_amdgcn_readfirstlane(cbk * 64 + g * 16);
  const int t = t0 + lane_t;
  float acc[16];
#pragma unroll
  for (int j = 0; j < 16; ++j) acc[j] = 0.f;
  const float* wbase = wT + ((size_t)ks * CINC * K) * COUT;
  const int col0 = t0 * S;

  for (int c0 = 0; c0 < CINC; c0 += CC) {
    __syncthreads();
    for (int e = tid; e < CC * SPAN; e += 256) {
      int cc = e / SPAN, col = e - cc * SPAN;
      int ti = col0 + col;
      int gci = ks * CINC + c0 + cc;
      float v = 0.f;
      if (ti < TIN) {
        size_t off = (size_t)b * (512 * 114) + (size_t)gci * 114 + ti;
        v = pin[off] + pin[off + p1Off] + b5[gci];
      }
      xs[e] = v;
    }
    __syncthreads();

    const float* wchunk = wbase + ((size_t)c0 * K) * COUT + coutBase;
    for (int cc = 0; cc < CC; ++cc) {
#pragma unroll
      for (int kk = 0; kk < K; ++kk) {
        const float* wrow = wchunk + (size_t)(cc * K + kk) * COUT;
        float wv[16];
#pragma unroll
        for (int j = 0; j < 16; ++j) wv[j] = wrow[j];
        float xv = xs[cc * SPAN + lane_t * S + kk];
#pragma unroll
        for (int j = 0; j < 16; ++j) acc[j] += xv * wv[j];
      }
    }
  }
  if (t < 57) {
#pragma unroll
    for (int j = 0; j < 16; ++j) {
      int co = coutBase + j;
      p[(size_t)ks * ksStrideP + ((size_t)b * COUT + co) * 57 + t] = acc[j];
    }
  }
}

// ---------------- reduce K-split partials + bias
template<int COUT, int TOUT, int KS>
__global__ __launch_bounds__(256) void redbias_k(
    const float* __restrict__ p, const float* __restrict__ bias,
    float* __restrict__ y, int ksStride, int n)
{
  int idx = blockIdx.x * 256 + threadIdx.x;
  if (idx >= n) return;
  int c = (idx / TOUT) % COUT;
  float s = p[idx];
#pragma unroll
  for (int ks = 1; ks < KS; ++ks) s += p[idx + (size_t)ks * ksStride];
  y[idx] = s + bias[c];
}

// ---------------- inverse transpose yattn [B,57,512] -> yT [B,512,57]
__global__ __launch_bounds__(256) void itranspose_k(const float* __restrict__ y,
                                                    float* __restrict__ yT)
{
  const int b = blockIdx.y, dt = blockIdx.x;
  __shared__ float tile[32 * 58];
  const int tid = threadIdx.x;
  const int d0 = dt * 32;
  for (int e = tid; e < L_ * 32; e += 256) {
    int l = e >> 5, dd = e & 31;
    tile[dd * 58 + l] = y[((size_t)b * L_ + l) * D_ + d0 + dd];
  }
  __syncthreads();
  for (int e = tid; e < 32 * L_; e += 256) {
    int dd = e / L_, l = e - dd * L_;
    yT[((size_t)b * D_ + d0 + dd) * L_ + l] = tile[dd * 58 + l];
  }
}

// ---------------- QKV GEMM
__global__ __launch_bounds__(256, 2) void qkvgemm_k(
    const float* __restrict__ c6, const float* __restrict__ wqkvT,
    float* __restrict__ q, float* __restrict__ k, float* __restrict__ v)
{
  const int ot = blockIdx.x, b = blockIdx.y;
  const int tid = threadIdx.x;
  const int w = tid >> 6, lane = tid & 63;
  const int lrow = lane >> 3, ncol = lane & 7;
  __shared__ __align__(16) float As[32 * 68];
  __shared__ __align__(16) float Bs[32 * 256];
  float acc[8][8];
#pragma unroll
  for (int li = 0; li < 8; ++li)
#pragma unroll
    for (int nj = 0; nj < 8; ++nj) acc[li][nj] = 0.f;

  const float* c6b = c6 + (size_t)b * D_ * L_;
  const int o0 = ot * 256;

  for (int d0 = 0; d0 < D_; d0 += 32) {
    __syncthreads();
#pragma unroll
    for (int i = 0; i < 8; ++i) {
      int e = tid + i * 256;
      int dd = e >> 6, l = e & 63;
      As[dd * 68 + l] = (l < L_) ? c6b[(size_t)(d0 + dd) * L_ + l] : 0.f;
    }
#pragma unroll
    for (int i = 0; i < 8; ++i) {
      int e = tid + i * 256;
      int dd = e >> 6, o4 = (e & 63) * 4;
      *reinterpret_cast<float4*>(&Bs[dd * 256 + o4]) =
          *reinterpret_cast<const float4*>(&wqkvT[(size_t)(d0 + dd) * 1536 + o0 + o4]);
    }
    __syncthreads();
#pragma unroll 4
    for (int dd = 0; dd < 32; ++dd) {
      float a8[8], b8[8];
      *reinterpret_cast<float4*>(&a8[0]) = *reinterpret_cast<const float4*>(&As[dd * 68 + lrow * 8]);
      *reinterpret_cast<float4*>(&a8[4]) = *reinterpret_cast<const float4*>(&As[dd * 68 + lrow * 8 + 4]);
      *reinterpret_cast<float4*>(&b8[0]) = *reinterpret_cast<const float4*>(&Bs[dd * 256 + w * 64 + ncol * 8]);
      *reinterpret_cast<float4*>(&b8[4]) = *reinterpret_cast<const float4*>(&Bs[dd * 256 + w * 64 + ncol * 8 + 4]);
#pragma unroll
      for (int li = 0; li < 8; ++li)
#pragma unroll
        for (int nj = 0; nj < 8; ++nj)
          acc[li][nj] += a8[li] * b8[nj];
    }
  }

  const int o3 = o0 + w * 64 + ncol * 8;
  const int set = __builtin_amdgcn_readfirstlane(o3 >> 9);
  const int h = (o3 >> 6) & 7, kd = o3 & 63;
  float* OUT = (set == 0 ? q : (set == 1 ? k : v));
  float* base = OUT + (((size_t)b * H_ + h) * L_) * DK_ + kd;
#pragma unroll
  for (int li = 0; li < 8; ++li) {
    int l = lrow * 8 + li;
    if (l < L_) {
      float* p = base + (size_t)l * DK_;
      *reinterpret_cast<float4*>(p)     = *reinterpret_cast<float4*>(&acc[li][0]);
      *reinterpret_cast<float4*>(p + 4) = *reinterpret_cast<float4*>(&acc[li][4]);
    }
  }
}

// ---------------- attention per (b,h)
__global__ __launch_bounds__(256) void attn_k(
    const float* __restrict__ q, const float* __restrict__ k, const float* __restrict__ v,
    float* __restrict__ cat)
{
  const int bh = blockIdx.x;
  const int b = bh >> 3, h = bh & 7;
  __shared__ float qs[L_ * DK_];
  __shared__ float ks[L_ * 65];
  __shared__ float vs[L_ * DK_];
  __shared__ float ps[L_ * DK_];
  const int tid = threadIdx.x;
  const float* qb = q + (size_t)bh * L_ * DK_;
  const float* kb = k + (size_t)bh * L_ * DK_;
  const float* vb = v + (size_t)bh * L_ * DK_;
  for (int e = tid; e < L_ * DK_; e += 256) {
    qs[e] = qb[e];
    vs[e] = vb[e];
    int m = e >> 6, d = e & 63;
    ks[m * 65 + d] = kb[e];
  }
  __syncthreads();
  for (int e = tid; e < L_ * L_; e += 256) {
    int l = e / L_, m = e - (e / L_) * L_;
    float s = 0.f;
#pragma unroll
    for (int d = 0; d < DK_; ++d) s += qs[l * DK_ + d] * ks[m * 65 + d];
    ps[l * DK_ + m] = s * 0.125f;
  }
  __syncthreads();
  if (tid < L_) {
    float mx = -1e30f;
    for (int m = 0; m < L_; ++m) mx = fmaxf(mx, ps[tid * DK_ + m]);
    float sum = 0.f;
    for (int m = 0; m < L_; ++m) { float e2 = __expf(ps[tid * DK_ + m] - mx); ps[tid * DK_ + m] = e2; sum += e2; }
    float inv = 1.f / sum;
    for (int m = 0; m < L_; ++m) ps[tid * DK_ + m] *= inv;
  }
  __syncthreads();
  for (int e = tid; e < L_ * DK_; e += 256) {
    int l = e >> 6, kd = e & 63;
    float s = 0.f;
    for (int m = 0; m < L_; ++m) s += ps[l * DK_ + m] * vs[m * DK_ + kd];
    cat[((size_t)b * L_ + l) * D_ + h * DK_ + kd] = s;
  }
}

// ---------------- output projection (o-split)
__global__ __launch_bounds__(256) void outproj_k(
    const float* __restrict__ cat, const float* __restrict__ wo,
    const float* __restrict__ bo, float* __restrict__ y)
{
  const int b = blockIdx.y;
  const int lt = blockIdx.x >> 1;
  const int half = blockIdx.x & 1;
  const int l0 = lt * 16;
  const int o = half * 256 + threadIdx.x;
  __shared__ __align__(16) float cs[16 * D_];
  const int tid = threadIdx.x;
  for (int e = tid; e < 16 * D_; e += 256) {
    int l = l0 + (e >> 9);
    cs[e] = (l < L_) ? cat[((size_t)b * L_ + l) * D_ + (e & 511)] : 0.f;
  }
  __syncthreads();
  float acc[16];
#pragma unroll
  for (int j = 0; j < 16; ++j) acc[j] = 0.f;
  for (int d = 0; d < D_; d += 4) {
    float w0 = wo[(size_t)d * D_ + o];
    float w1 = wo[(size_t)(d + 1) * D_ + o];
    float w2 = wo[(size_t)(d + 2) * D_ + o];
    float w3 = wo[(size_t)(d + 3) * D_ + o];
#pragma unroll
    for (int j = 0; j < 16; ++j) {
      const float4 c4 = *reinterpret_cast<const float4*>(&cs[j * D_ + d]);
      acc[j] += c4.x * w0 + c4.y * w1 + c4.z * w2 + c4.w * w3;
    }
  }
  float bv = bo[o];
#pragma unroll
  for (int j = 0; j < 16; ++j) {
    int l = l0 + j;
    if (l < L_) y[((size_t)b * L_ + l) * D_ + o] = acc[j] + bv;
  }
}

// ---------------- codebook prep
__global__ __launch_bounds__(64) void cbprep_k(const float* __restrict__ cb,
                                               float* __restrict__ cbT,
                                               float* __restrict__ cnorm)
{
  const int n = blockIdx.x, t = threadIdx.x;
  float s = 0.f;
  for (int d = t; d < D_; d += 64) {
    float vv = cb[(size_t)n * D_ + d];
    cbT[(size_t)d * NC_ + n] = vv;
    s += vv * vv;
  }
#pragma unroll
  for (int off = 32; off >= 1; off >>= 1) s += __shfl_xor(s, off);
  if (t == 0) cnorm[n] = s;
}

// ---------------- VQ distance GEMM + partial argmin
__global__ __launch_bounds__(256, 2) void vqgemm_k(
    const float* __restrict__ yT, const float* __restrict__ cbT,
    const float* __restrict__ cnorm, float* __restrict__ pmin, int* __restrict__ pidx)
{
  const int b = blockIdx.y, nt = blockIdx.x;
  const int tid = threadIdx.x;
  const int w = tid >> 6, lane = tid & 63;
  const int lrow = lane >> 3, ncol = lane & 7;
  __shared__ __align__(16) float As[32 * 68];
  __shared__ __align__(16) float Bs[32 * 256];
  __shared__ float redv[4][64];
  __shared__ int   redi[4][64];
  float acc[8][8];
#pragma unroll
  for (int li = 0; li < 8; ++li)
#pragma unroll
    for (int nj = 0; nj < 8; ++nj) acc[li][nj] = 0.f;

  const float* yTb = yT + (size_t)b * D_ * L_;
  const int n0 = nt * 256;
  const int nbase = n0 + w * 64 + ncol * 8;

  for (int d0 = 0; d0 < D_; d0 += 32) {
    __syncthreads();
#pragma unroll
    for (int i = 0; i < 8; ++i) {
      int e = tid + i * 256;
      int dd = e >> 6, l = e & 63;
      As[dd * 68 + l] = (l < L_) ? yTb[(size_t)(d0 + dd) * L_ + l] : 0.f;
    }
#pragma unroll
    for (int i = 0; i < 8; ++i) {
      int e = tid + i * 256;
      int dd = e >> 6, n4 = (e & 63) * 4;
      *reinterpret_cast<float4*>(&Bs[dd * 256 + n4]) =
          *reinterpret_cast<const float4*>(&cbT[(size_t)(d0 + dd) * NC_ + n0 + n4]);
    }
    __syncthreads();
#pragma unroll 4
    for (int dd = 0; dd < 32; ++dd) {
      float a8[8], b8[8];
      *reinterpret_cast<float4*>(&a8[0]) = *reinterpret_cast<const float4*>(&As[dd * 68 + lrow * 8]);
      *reinterpret_cast<float4*>(&a8[4]) = *reinterpret_cast<const float4*>(&As[dd * 68 + lrow * 8 + 4]);
      *reinterpret_cast<float4*>(&b8[0]) = *reinterpret_cast<const float4*>(&Bs[dd * 256 + w * 64 + ncol * 8]);
      *reinterpret_cast<float4*>(&b8[4]) = *reinterpret_cast<const float4*>(&Bs[dd * 256 + w * 64 + ncol * 8 + 4]);
#pragma unroll
      for (int li = 0; li < 8; ++li)
#pragma unroll
        for (int nj = 0; nj < 8; ++nj)
          acc[li][nj] += a8[li] * b8[nj];
    }
  }

  float cn[8];
  *reinterpret_cast<float4*>(&cn[0]) = *reinterpret_cast<const float4*>(&cnorm[nbase]);
  *reinterpret_cast<float4*>(&cn[4]) = *reinterpret_cast<const float4*>(&cnorm[nbase + 4]);
#pragma unroll
  for (int li = 0; li < 8; ++li) {
    float vb = cn[0] - 2.f * acc[li][0];
    int ib = nbase;
#pragma unroll
    for (int nj = 1; nj < 8; ++nj) {
      float v = cn[nj] - 2.f * acc[li][nj];
      if (v < vb) { vb = v; ib = nbase + nj; }
    }
#pragma unroll
    for (int off = 1; off <= 4; off <<= 1) {
      float vo = __shfl_xor(vb, off);
      int io = __shfl_xor(ib, off);
      if (vo < vb || (vo == vb && io < ib)) { vb = vo; ib = io; }
    }
    if (ncol == 0) { redv[w][lrow * 8 + li] = vb; redi[w][lrow * 8 + li] = ib; }
  }
  __syncthreads();
  if (tid < L_) {
    float vb = redv[0][tid]; int ib = redi[0][tid];
#pragma unroll
    for (int w2 = 1; w2 < 4; ++w2) {
      float vo = redv[w2][tid]; int io = redi[w2][tid];
      if (vo < vb || (vo == vb && io < ib)) { vb = vo; ib = io; }
    }
    pmin[((size_t)b * L_ + tid) * 8 + nt] = vb;
    pidx[((size_t)b * L_ + tid) * 8 + nt] = ib;
  }
}

// ---------------- VQ final
__global__ __launch_bounds__(64) void vqfin_k(
    const float* __restrict__ y, const float* __restrict__ cbook,
    const float* __restrict__ pmin, const int* __restrict__ pidx,
    float* __restrict__ zq, float* __restrict__ oidx, float* __restrict__ lpart)
{
  const int bl = blockIdx.x;
  const int tid = threadIdx.x;
  __shared__ int sidx;
  if (tid == 0) {
    float vb = pmin[(size_t)bl * 8];
    int ib = pidx[(size_t)bl * 8];
    for (int ntv = 1; ntv < 8; ++ntv) {
      float vo = pmin[(size_t)bl * 8 + ntv];
      int io = pidx[(size_t)bl * 8 + ntv];
      if (vo < vb || (vo == vb && io < ib)) { vb = vo; ib = io; }
    }
    sidx = ib;
  }
  __syncthreads();
  const int idx = sidx;
  const float* crow = cbook + (size_t)idx * D_;
  const float* yrow = y + (size_t)bl * D_;
  float s = 0.f;
  for (int d = tid; d < D_; d += 64) {
    float c = crow[d];
    float df = c - yrow[d];
    zq[(size_t)bl * D_ + d] = c;
    s += df * df;
  }
#pragma unroll
  for (int off = 32; off >= 1; off >>= 1) s += __shfl_xor(s, off);
  if (tid == 0) { lpart[bl] = s; oidx[bl] = (float)idx; }
}

// ---------------- loss reduce
__global__ __launch_bounds__(256) void loss_k(const float* __restrict__ lpart,
                                              float* __restrict__ outLoss)
{
  const int tid = threadIdx.x;
  float s = 0.f;
  for (int i = tid; i < B_ * L_; i += 256) s += lpart[i];
  __shared__ float red[256];
  red[tid] = s;
  __syncthreads();
  for (int off = 128; off >= 1; off >>= 1) {
    if (tid < off) red[tid] += red[tid + off];
    __syncthreads();
  }
  if (tid == 0) outLoss[0] = red[0] * ((1.f + 0.2f) / (float)((size_t)B_ * L_ * D_));
}

extern "C" void kernel_launch(void* const* d_in, const int* in_sizes, int n_in,
                              void* d_out, int out_size, void* d_ws, size_t ws_size,
                              hipStream_t stream)
{
  const float* x  = (const float*)d_in[0];
  const float* w1 = (const float*)d_in[1];  const float* b1 = (const float*)d_in[2];
  const float* w2 = (const float*)d_in[3];  const float* b2 = (const float*)d_in[4];
  const float* w3 = (const float*)d_in[5];  const float* b3 = (const float*)d_in[6];
  const float* w4 = (const float*)d_in[7];  const float* b4 = (const float*)d_in[8];
  const float* w5 = (const float*)d_in[9];  const float* b5 = (const float*)d_in[10];
  const float* w6 = (const float*)d_in[11]; const float* b6 = (const float*)d_in[12];
  const float* wq = (const float*)d_in[13];
  const float* wk = (const float*)d_in[14];
  const float* wv = (const float*)d_in[15];
  const float* wo = (const float*)d_in[16];
  const float* bo = (const float*)d_in[17];
  const float* cbook = (const float*)d_in[18];

  float* ws = (float*)d_ws;
  // wT region (wT1 zero-padded to 112 cins = 1120 rows)
  float* wT1 = ws;                  // 71,680
  float* wT2 = ws + 71680;          // 24,576
  float* wT3 = ws + 96256;          // 98,304
  float* wT4 = ws + 194560;         // 393,216
  float* wT5 = ws + 587776;         // 524,288
  float* wT6 = ws + 1112064;        // 524,288 -> ends 1,636,352

  // Full-batch layout needs 18,507,840 floats (74.04 MB).
  const bool FULL = (ws_size >= (size_t)18507840 * 4);

  // conv weight re-layouts (wT1 padded; rows 0..1049 identical to unpadded)
  wtransp_k<<<(1120 * 64 + 255) / 256, 256, 0, stream>>>(w1, wT1, 1050, 1120, 64);
  wtrans_k<<<( 192 * 128 + 255) / 256, 256, 0, stream>>>(w2, wT2, 192, 128);
  wtrans_k<<<( 384 * 256 + 255) / 256, 256, 0, stream>>>(w3, wT3, 384, 256);
  wtrans_k<<<( 768 * 512 + 255) / 256, 256, 0, stream>>>(w4, wT4, 768, 512);
  wtrans_k<<<(1024 * 512 + 255) / 256, 256, 0, stream>>>(w5, wT5, 1024, 512);
  wtrans_k<<<(1024 * 512 + 255) / 256, 256, 0, stream>>>(w6, wT6, 1024, 512);

  float* c6;
  if (FULL) {
    // ---- Full-batch conv; conv1 = 2-way K-split TT=128 (partials at P and
    //      P+7,500,032; in-place reduce into P covering ALL 7,499,776
    //      elements = 64b x 64cout x 1831t), conv2-5 TT=128, conv5/6 K-split
    float* P = ws + 1640000;        // 7,500,032 -> ends 9,140,032
    float* Q = ws + 9140032;        // 7,500,032 -> ends 16,640,064
    c6 = ws + 16640064;
    conv1ksw_k<<<dim3(15,2,B_),256,0,stream>>>(x, wT1, P, 7500032);
    redbias_k<64,1831,2><<<(7499776 + 255) / 256, 256, 0, stream>>>(
        P, b1, P, 7500032, 7499776);
    conv1dw_k< 64, 3,2,128,32><<<dim3( 8,2,B_),256,0,stream>>>(P, wT2,b2, Q, 1831, 915);
    conv1dw_k<128, 3,2,256,32><<<dim3( 4,4,B_),256,0,stream>>>(Q, wT3,b3, P,  915, 457);
    conv1dw_k<256, 3,2,512,32><<<dim3( 2,8,B_),256,0,stream>>>(P, wT4,b4, Q,  457, 228);
    convksw_k<256,2,2,512,32,2><<<dim3(1,16,B_),256,0,stream>>>(
        Q, wT5, P, 228, 114, 512 * 228, 3735552);
    convks6f_k<<<dim3(1,32,B_),256,0,stream>>>(P, wT6, b5, Q, 3735552, 1867776);
    redbias_k<512,57,4><<<(1867776 + 255) / 256, 256, 0, stream>>>(
        Q, b6, c6, 1867776, 1867776);
  } else {
    // ---- Half-batch fallback (proven TT=64 path; buffers after new wT) ----
    float* bufA = ws + 1640000;
    float* bufB = ws + 5390016;
    c6 = ws + 9140032;
    for (int h = 0; h < 2; ++h) {
      const float* xh = x + (size_t)h * HB_ * 105 * 5500;
      float* c6h = c6 + (size_t)h * HB_ * D_ * L_;
      conv1d_k<105,10,3, 64,21><<<dim3(29,1,HB_),256,0,stream>>>(xh,   wT1,b1, bufA, 5500,1831);
      conv1d_k< 64, 3,2,128,32><<<dim3(15,2,HB_),256,0,stream>>>(bufA, wT2,b2, bufB, 1831, 915);
      conv1d_k<128, 3,2,256,32><<<dim3( 8,4,HB_),256,0,stream>>>(bufB, wT3,b3, bufA,  915, 457);
      conv1d_k<256, 3,2,512,32><<<dim3( 4,8,HB_),256,0,stream>>>(bufA, wT4,b4, bufB,  457, 228);
      convks_k<256,2,2,512,32,2><<<dim3(2,16,HB_),256,0,stream>>>(
          bufB, wT5, bufA, 228, 114, 512 * 228, 1867776);
      convks6f_k<<<dim3(1,32,HB_),256,0,stream>>>(
          bufA, wT6, b5, bufB, 1867776, 933888);
      redbias_k<512,57,4><<<(933888 + 255) / 256, 256, 0, stream>>>(
          bufB, b6, c6h, 933888, 933888);
    }
  }

  // post-conv regions (conv scratch dead; offsets clear of c6 in both layouts)
  float* qb     = ws;               // 1,867,776
  float* kb     = ws + 1867776;
  float* vb     = ws + 3735552;     // ends 5,603,328
  float* wqkvT  = ws + 5603328;     // 786,432
  float* cat    = ws + 7471104;     // 1,867,776
  float* yattn  = ws;               // (qb dead after attn)
  float* yT     = ws + 1867776;     // (kb dead after attn)
  float* cbT    = ws + 11206656;    // 1,048,576
  float* cnorm  = ws + 12255232;    // 2,048
  float* pminb  = ws + 12257280;    // 29,184
  int*   pidxb  = (int*)(ws + 12286464); // 29,184
  float* lpart  = ws + 12315648;    // 3,648

  float* zq      = (float*)d_out;
  float* outLoss = zq + (size_t)B_ * L_ * D_;
  float* outIdx  = outLoss + 1;

  // attention (QKV reads c6 directly in [d][l] layout)
  wqkvprep_k<<<(786432 + 255) / 256, 256, 0, stream>>>(wq, wk, wv, wqkvT);
  qkvgemm_k<<<dim3(6, B_), 256, 0, stream>>>(c6, wqkvT, qb, kb, vb);
  cbprep_k<<<NC_, 64, 0, stream>>>(cbook, cbT, cnorm);
  attn_k<<<B_ * H_, 256, 0, stream>>>(qb, kb, vb, cat);
  outproj_k<<<dim3(8, B_), 256, 0, stream>>>(cat, wo, bo, yattn);

  itranspose_k<<<dim3(16, B_), 256, 0, stream>>>(yattn, yT);
  vqgemm_k<<<dim3(8, B_), 256, 0, stream>>>(yT, cbT, cnorm, pminb, pidxb);
  vqfin_k<<<B_ * L_, 64, 0, stream>>>(yattn, cbook, pminb, pidxb, zq, outIdx, lpart);
  loss_k<<<1, 256, 0, stream>>>(lpart, outLoss);
}

// Round 20
// 1182.690 us; speedup vs baseline: 1.0097x; 1.0097x over previous
//
#include <hip/hip_runtime.h>
#include <hip/hip_bf16.h>
#include <math.h>

#define B_ 64
#define HB_ 32
#define L_ 57
#define D_ 512
#define H_ 8
#define DK_ 64
#define NC_ 2048

// ---------------- weight transpose: w[cout][cin][k] -> wT[cin*K + k][cout]
__global__ __launch_bounds__(256) void wtrans_k(const float* __restrict__ w,
                                                float* __restrict__ wT,
                                                int CINK, int COUT)
{
  int idx = blockIdx.x * 256 + threadIdx.x;
  if (idx >= CINK * COUT) return;
  int r = idx / COUT, c = idx - r * COUT;
  wT[idx] = w[(size_t)c * CINK + r];
}

// ---------------- qkv weight prep
__global__ __launch_bounds__(256) void wqkvprep_k(
    const float* __restrict__ wq, const float* __restrict__ wk,
    const float* __restrict__ wv, float* __restrict__ wqkvT)
{
  int idx = blockIdx.x * 256 + threadIdx.x;   // 3*512*512 = 786432
  if (idx >= 786432) return;
  int set = idx >> 18;
  int h   = (idx >> 15) & 7;
  int d   = (idx >> 6) & 511;
  int kd  = idx & 63;
  const float* W = (set == 0 ? wq : (set == 1 ? wk : wv));
  float v = W[((size_t)h * 512 + d) * 64 + kd];
  wqkvT[(size_t)d * 1536 + set * 512 + h * 64 + kd] = v;
}

// ---------------- conv1d TT=64 (fallback path)
template<int CIN, int K, int S, int COUT, int CC>
__global__ __launch_bounds__(256, 4) void conv1d_k(
    const float* __restrict__ x, const float* __restrict__ wT,
    const float* __restrict__ bias, float* __restrict__ y,
    int Tin, int Tout)
{
  constexpr int TT = 64;
  constexpr int SPAN = S * TT + K - S;
  __shared__ float xs[CC * SPAN];
  const int b   = blockIdx.z;
  const int cbk = blockIdx.y;
  const int t0  = blockIdx.x * TT;
  const int tid = threadIdx.x;
  const int lane_t = tid & 63;
  const int g = tid >> 6;
  const int coutBase = __builtin_amdgcn_readfirstlane(cbk * 64 + g * 16);
  const int t = t0 + lane_t;
  float acc[16];
#pragma unroll
  for (int j = 0; j < 16; ++j) acc[j] = 0.f;
  const float* xb = x + (size_t)b * CIN * Tin;
  const int col0 = t0 * S;

  for (int c0 = 0; c0 < CIN; c0 += CC) {
    __syncthreads();
    for (int e = tid; e < CC * SPAN; e += 256) {
      int cc = e / SPAN, col = e - cc * SPAN;
      int ti = col0 + col;
      xs[e] = (ti < Tin) ? xb[(size_t)(c0 + cc) * Tin + ti] : 0.f;
    }
    __syncthreads();

    const float* wchunk = wT + ((size_t)c0 * K) * COUT + coutBase;
    for (int cc = 0; cc < CC; ++cc) {
#pragma unroll
      for (int kk = 0; kk < K; ++kk) {
        const float* wrow = wchunk + (size_t)(cc * K + kk) * COUT;
        float wv[16];
#pragma unroll
        for (int j = 0; j < 16; ++j) wv[j] = wrow[j];
        float xv = xs[cc * SPAN + lane_t * S + kk];
#pragma unroll
        for (int j = 0; j < 16; ++j) acc[j] += xv * wv[j];
      }
    }
  }
  if (t < Tout) {
#pragma unroll
    for (int j = 0; j < 16; ++j) {
      int co = coutBase + j;
      y[((size_t)b * COUT + co) * Tout + t] = acc[j] + bias[co];
    }
  }
}

// ---------------- conv1d TT=128: 2 t/lane -> 32 FMA per weight-row stall
template<int CIN, int K, int S, int COUT, int CC>
__global__ __launch_bounds__(256, 4) void conv1dw_k(
    const float* __restrict__ x, const float* __restrict__ wT,
    const float* __restrict__ bias, float* __restrict__ y,
    int Tin, int Tout)
{
  constexpr int TT = 128;
  constexpr int SPAN = S * TT + K - S;
  __shared__ float xs[CC * SPAN];
  const int b   = blockIdx.z;
  const int cbk = blockIdx.y;
  const int t0  = blockIdx.x * TT;
  const int tid = threadIdx.x;
  const int lane_t = tid & 63;
  const int g = tid >> 6;
  const int coutBase = __builtin_amdgcn_readfirstlane(cbk * 64 + g * 16);
  float acc0[16], acc1[16];
#pragma unroll
  for (int j = 0; j < 16; ++j) { acc0[j] = 0.f; acc1[j] = 0.f; }
  const float* xb = x + (size_t)b * CIN * Tin;
  const int col0 = t0 * S;

  for (int c0 = 0; c0 < CIN; c0 += CC) {
    __syncthreads();
    for (int e = tid; e < CC * SPAN; e += 256) {
      int cc = e / SPAN, col = e - cc * SPAN;
      int ti = col0 + col;
      xs[e] = (ti < Tin) ? xb[(size_t)(c0 + cc) * Tin + ti] : 0.f;
    }
    __syncthreads();

    const float* wchunk = wT + ((size_t)c0 * K) * COUT + coutBase;
    for (int cc = 0; cc < CC; ++cc) {
#pragma unroll
      for (int kk = 0; kk < K; ++kk) {
        const float* wrow = wchunk + (size_t)(cc * K + kk) * COUT;
        float wv[16];
#pragma unroll
        for (int j = 0; j < 16; ++j) wv[j] = wrow[j];
        float xv0 = xs[cc * SPAN + lane_t * S + kk];
        float xv1 = xs[cc * SPAN + (lane_t + 64) * S + kk];
#pragma unroll
        for (int j = 0; j < 16; ++j) {
          acc0[j] += xv0 * wv[j];
          acc1[j] += xv1 * wv[j];
        }
      }
    }
  }
  const int t_a = t0 + lane_t, t_b = t0 + 64 + lane_t;
#pragma unroll
  for (int j = 0; j < 16; ++j) {
    int co = coutBase + j;
    float bv = bias[co];
    float* yr = y + ((size_t)b * COUT + co) * Tout;
    if (t_a < Tout) yr[t_a] = acc0[j] + bv;
    if (t_b < Tout) yr[t_b] = acc1[j] + bv;
  }
}

// ---------------- K-split conv TT=64 (fallback conv5)
template<int CINC, int K, int S, int COUT, int CC, int KS>
__global__ __launch_bounds__(256, 4) void convks_k(
    const float* __restrict__ x, const float* __restrict__ wT,
    float* __restrict__ p, int Tin, int Tout, int bStrideX, int ksStrideP)
{
  constexpr int TT = 64;
  constexpr int SPAN = S * TT + K - S;
  __shared__ float xs[CC * SPAN];
  const int b   = blockIdx.z;
  const int cbk = blockIdx.y & 7;
  const int ks  = blockIdx.y >> 3;
  const int t0  = blockIdx.x * TT;
  const int tid = threadIdx.x;
  const int lane_t = tid & 63;
  const int g = tid >> 6;
  const int coutBase = __builtin_amdgcn_readfirstlane(cbk * 64 + g * 16);
  const int t = t0 + lane_t;
  float acc[16];
#pragma unroll
  for (int j = 0; j < 16; ++j) acc[j] = 0.f;
  const float* xb = x + (size_t)b * bStrideX + (size_t)ks * CINC * Tin;
  const float* wbase = wT + ((size_t)ks * CINC * K) * COUT;
  const int col0 = t0 * S;

  for (int c0 = 0; c0 < CINC; c0 += CC) {
    __syncthreads();
    for (int e = tid; e < CC * SPAN; e += 256) {
      int cc = e / SPAN, col = e - cc * SPAN;
      int ti = col0 + col;
      xs[e] = (ti < Tin) ? xb[(size_t)(c0 + cc) * Tin + ti] : 0.f;
    }
    __syncthreads();

    const float* wchunk = wbase + ((size_t)c0 * K) * COUT + coutBase;
    for (int cc = 0; cc < CC; ++cc) {
#pragma unroll
      for (int kk = 0; kk < K; ++kk) {
        const float* wrow = wchunk + (size_t)(cc * K + kk) * COUT;
        float wv[16];
#pragma unroll
        for (int j = 0; j < 16; ++j) wv[j] = wrow[j];
        float xv = xs[cc * SPAN + lane_t * S + kk];
#pragma unroll
        for (int j = 0; j < 16; ++j) acc[j] += xv * wv[j];
      }
    }
  }
  if (t < Tout) {
#pragma unroll
    for (int j = 0; j < 16; ++j) {
      int co = coutBase + j;
      p[(size_t)ks * ksStrideP + ((size_t)b * COUT + co) * Tout + t] = acc[j];
    }
  }
}

// ---------------- K-split conv TT=128 (full-batch conv5)
template<int CINC, int K, int S, int COUT, int CC, int KS>
__global__ __launch_bounds__(256, 4) void convksw_k(
    const float* __restrict__ x, const float* __restrict__ wT,
    float* __restrict__ p, int Tin, int Tout, int bStrideX, int ksStrideP)
{
  constexpr int TT = 128;
  constexpr int SPAN = S * TT + K - S;
  __shared__ float xs[CC * SPAN];
  const int b   = blockIdx.z;
  const int cbk = blockIdx.y & 7;
  const int ks  = blockIdx.y >> 3;
  const int t0  = blockIdx.x * TT;
  const int tid = threadIdx.x;
  const int lane_t = tid & 63;
  const int g = tid >> 6;
  const int coutBase = __builtin_amdgcn_readfirstlane(cbk * 64 + g * 16);
  float acc0[16], acc1[16];
#pragma unroll
  for (int j = 0; j < 16; ++j) { acc0[j] = 0.f; acc1[j] = 0.f; }
  const float* xb = x + (size_t)b * bStrideX + (size_t)ks * CINC * Tin;
  const float* wbase = wT + ((size_t)ks * CINC * K) * COUT;
  const int col0 = t0 * S;

  for (int c0 = 0; c0 < CINC; c0 += CC) {
    __syncthreads();
    for (int e = tid; e < CC * SPAN; e += 256) {
      int cc = e / SPAN, col = e - cc * SPAN;
      int ti = col0 + col;
      xs[e] = (ti < Tin) ? xb[(size_t)(c0 + cc) * Tin + ti] : 0.f;
    }
    __syncthreads();

    const float* wchunk = wbase + ((size_t)c0 * K) * COUT + coutBase;
    for (int cc = 0; cc < CC; ++cc) {
#pragma unroll
      for (int kk = 0; kk < K; ++kk) {
        const float* wrow = wchunk + (size_t)(cc * K + kk) * COUT;
        float wv[16];
#pragma unroll
        for (int j = 0; j < 16; ++j) wv[j] = wrow[j];
        float xv0 = xs[cc * SPAN + lane_t * S + kk];
        float xv1 = xs[cc * SPAN + (lane_t + 64) * S + kk];
#pragma unroll
        for (int j = 0; j < 16; ++j) {
          acc0[j] += xv0 * wv[j];
          acc1[j] += xv1 * wv[j];
        }
      }
    }
  }
  const int t_a = t0 + lane_t, t_b = t0 + 64 + lane_t;
#pragma unroll
  for (int j = 0; j < 16; ++j) {
    int co = coutBase + j;
    float* pr = p + (size_t)ks * ksStrideP + ((size_t)b * COUT + co) * Tout;
    if (t_a < Tout) pr[t_a] = acc0[j];
    if (t_b < Tout) pr[t_b] = acc1[j];
  }
}

// ---------------- conv6 with fused conv5-reduce
__global__ __launch_bounds__(256, 4) void convks6f_k(
    const float* __restrict__ pin, const float* __restrict__ wT,
    const float* __restrict__ b5, float* __restrict__ p,
    int p1Off, int ksStrideP)
{
  constexpr int CINC = 128, K = 2, S = 2, COUT = 512, CC = 32, TT = 64;
  constexpr int SPAN = S * TT + K - S;   // 128
  constexpr int TIN = 114;
  __shared__ float xs[CC * SPAN];
  const int b   = blockIdx.z;
  const int cbk = blockIdx.y & 7;
  const int ks  = blockIdx.y >> 3;
  const int t0  = blockIdx.x * TT;
  const int tid = threadIdx.x;
  const int lane_t = tid & 63;
  const int g = tid >> 6;
  const int coutBase = __builtin_amdgcn_readfirstlane(cbk * 64 + g * 16);
  const int t = t0 + lane_t;
  float acc[16];
#pragma unroll
  for (int j = 0; j < 16; ++j) acc[j] = 0.f;
  const float* wbase = wT + ((size_t)ks * CINC * K) * COUT;
  const int col0 = t0 * S;

  for (int c0 = 0; c0 < CINC; c0 += CC) {
    __syncthreads();
    for (int e = tid; e < CC * SPAN; e += 256) {
      int cc = e / SPAN, col = e - cc * SPAN;
      int ti = col0 + col;
      int gci = ks * CINC + c0 + cc;
      float v = 0.f;
      if (ti < TIN) {
        size_t off = (size_t)b * (512 * 114) + (size_t)gci * 114 + ti;
        v = pin[off] + pin[off + p1Off] + b5[gci];
      }
      xs[e] = v;
    }
    __syncthreads();

    const float* wchunk = wbase + ((size_t)c0 * K) * COUT + coutBase;
    for (int cc = 0; cc < CC; ++cc) {
#pragma unroll
      for (int kk = 0; kk < K; ++kk) {
        const float* wrow = wchunk + (size_t)(cc * K + kk) * COUT;
        float wv[16];
#pragma unroll
        for (int j = 0; j < 16; ++j) wv[j] = wrow[j];
        float xv = xs[cc * SPAN + lane_t * S + kk];
#pragma unroll
        for (int j = 0; j < 16; ++j) acc[j] += xv * wv[j];
      }
    }
  }
  if (t < 57) {
#pragma unroll
    for (int j = 0; j < 16; ++j) {
      int co = coutBase + j;
      p[(size_t)ks * ksStrideP + ((size_t)b * COUT + co) * 57 + t] = acc[j];
    }
  }
}

// ---------------- reduce K-split partials + bias
template<int COUT, int TOUT, int KS>
__global__ __launch_bounds__(256) void redbias_k(
    const float* __restrict__ p, const float* __restrict__ bias,
    float* __restrict__ y, int ksStride, int n)
{
  int idx = blockIdx.x * 256 + threadIdx.x;
  if (idx >= n) return;
  int c = (idx / TOUT) % COUT;
  float s = p[idx];
#pragma unroll
  for (int ks = 1; ks < KS; ++ks) s += p[idx + (size_t)ks * ksStride];
  y[idx] = s + bias[c];
}

// ---------------- QKV GEMM
__global__ __launch_bounds__(256, 2) void qkvgemm_k(
    const float* __restrict__ c6, const float* __restrict__ wqkvT,
    float* __restrict__ q, float* __restrict__ k, float* __restrict__ v)
{
  const int ot = blockIdx.x, b = blockIdx.y;
  const int tid = threadIdx.x;
  const int w = tid >> 6, lane = tid & 63;
  const int lrow = lane >> 3, ncol = lane & 7;
  __shared__ __align__(16) float As[32 * 68];
  __shared__ __align__(16) float Bs[32 * 256];
  float acc[8][8];
#pragma unroll
  for (int li = 0; li < 8; ++li)
#pragma unroll
    for (int nj = 0; nj < 8; ++nj) acc[li][nj] = 0.f;

  const float* c6b = c6 + (size_t)b * D_ * L_;
  const int o0 = ot * 256;

  for (int d0 = 0; d0 < D_; d0 += 32) {
    __syncthreads();
#pragma unroll
    for (int i = 0; i < 8; ++i) {
      int e = tid + i * 256;
      int dd = e >> 6, l = e & 63;
      As[dd * 68 + l] = (l < L_) ? c6b[(size_t)(d0 + dd) * L_ + l] : 0.f;
    }
#pragma unroll
    for (int i = 0; i < 8; ++i) {
      int e = tid + i * 256;
      int dd = e >> 6, o4 = (e & 63) * 4;
      *reinterpret_cast<float4*>(&Bs[dd * 256 + o4]) =
          *reinterpret_cast<const float4*>(&wqkvT[(size_t)(d0 + dd) * 1536 + o0 + o4]);
    }
    __syncthreads();
#pragma unroll 4
    for (int dd = 0; dd < 32; ++dd) {
      float a8[8], b8[8];
      *reinterpret_cast<float4*>(&a8[0]) = *reinterpret_cast<const float4*>(&As[dd * 68 + lrow * 8]);
      *reinterpret_cast<float4*>(&a8[4]) = *reinterpret_cast<const float4*>(&As[dd * 68 + lrow * 8 + 4]);
      *reinterpret_cast<float4*>(&b8[0]) = *reinterpret_cast<const float4*>(&Bs[dd * 256 + w * 64 + ncol * 8]);
      *reinterpret_cast<float4*>(&b8[4]) = *reinterpret_cast<const float4*>(&Bs[dd * 256 + w * 64 + ncol * 8 + 4]);
#pragma unroll
      for (int li = 0; li < 8; ++li)
#pragma unroll
        for (int nj = 0; nj < 8; ++nj)
          acc[li][nj] += a8[li] * b8[nj];
    }
  }

  const int o3 = o0 + w * 64 + ncol * 8;
  const int set = __builtin_amdgcn_readfirstlane(o3 >> 9);
  const int h = (o3 >> 6) & 7, kd = o3 & 63;
  float* OUT = (set == 0 ? q : (set == 1 ? k : v));
  float* base = OUT + (((size_t)b * H_ + h) * L_) * DK_ + kd;
#pragma unroll
  for (int li = 0; li < 8; ++li) {
    int l = lrow * 8 + li;
    if (l < L_) {
      float* p = base + (size_t)l * DK_;
      *reinterpret_cast<float4*>(p)     = *reinterpret_cast<float4*>(&acc[li][0]);
      *reinterpret_cast<float4*>(p + 4) = *reinterpret_cast<float4*>(&acc[li][4]);
    }
  }
}

// ---------------- attention per (b,h)
__global__ __launch_bounds__(256) void attn_k(
    const float* __restrict__ q, const float* __restrict__ k, const float* __restrict__ v,
    float* __restrict__ cat)
{
  const int bh = blockIdx.x;
  const int b = bh >> 3, h = bh & 7;
  __shared__ float qs[L_ * DK_];
  __shared__ float ks[L_ * 65];
  __shared__ float vs[L_ * DK_];
  __shared__ float ps[L_ * DK_];
  const int tid = threadIdx.x;
  const float* qb = q + (size_t)bh * L_ * DK_;
  const float* kb = k + (size_t)bh * L_ * DK_;
  const float* vb = v + (size_t)bh * L_ * DK_;
  for (int e = tid; e < L_ * DK_; e += 256) {
    qs[e] = qb[e];
    vs[e] = vb[e];
    int m = e >> 6, d = e & 63;
    ks[m * 65 + d] = kb[e];
  }
  __syncthreads();
  for (int e = tid; e < L_ * L_; e += 256) {
    int l = e / L_, m = e - (e / L_) * L_;
    float s = 0.f;
#pragma unroll
    for (int d = 0; d < DK_; ++d) s += qs[l * DK_ + d] * ks[m * 65 + d];
    ps[l * DK_ + m] = s * 0.125f;
  }
  __syncthreads();
  if (tid < L_) {
    float mx = -1e30f;
    for (int m = 0; m < L_; ++m) mx = fmaxf(mx, ps[tid * DK_ + m]);
    float sum = 0.f;
    for (int m = 0; m < L_; ++m) { float e2 = __expf(ps[tid * DK_ + m] - mx); ps[tid * DK_ + m] = e2; sum += e2; }
    float inv = 1.f / sum;
    for (int m = 0; m < L_; ++m) ps[tid * DK_ + m] *= inv;
  }
  __syncthreads();
  for (int e = tid; e < L_ * DK_; e += 256) {
    int l = e >> 6, kd = e & 63;
    float s = 0.f;
    for (int m = 0; m < L_; ++m) s += ps[l * DK_ + m] * vs[m * DK_ + kd];
    cat[((size_t)b * L_ + l) * D_ + h * DK_ + kd] = s;
  }
}

// ---------------- output projection (o-split)
__global__ __launch_bounds__(256) void outproj_k(
    const float* __restrict__ cat, const float* __restrict__ wo,
    const float* __restrict__ bo, float* __restrict__ y)
{
  const int b = blockIdx.y;
  const int lt = blockIdx.x >> 1;
  const int half = blockIdx.x & 1;
  const int l0 = lt * 16;
  const int o = half * 256 + threadIdx.x;
  __shared__ __align__(16) float cs[16 * D_];
  const int tid = threadIdx.x;
  for (int e = tid; e < 16 * D_; e += 256) {
    int l = l0 + (e >> 9);
    cs[e] = (l < L_) ? cat[((size_t)b * L_ + l) * D_ + (e & 511)] : 0.f;
  }
  __syncthreads();
  float acc[16];
#pragma unroll
  for (int j = 0; j < 16; ++j) acc[j] = 0.f;
  for (int d = 0; d < D_; d += 4) {
    float w0 = wo[(size_t)d * D_ + o];
    float w1 = wo[(size_t)(d + 1) * D_ + o];
    float w2 = wo[(size_t)(d + 2) * D_ + o];
    float w3 = wo[(size_t)(d + 3) * D_ + o];
#pragma unroll
    for (int j = 0; j < 16; ++j) {
      const float4 c4 = *reinterpret_cast<const float4*>(&cs[j * D_ + d]);
      acc[j] += c4.x * w0 + c4.y * w1 + c4.z * w2 + c4.w * w3;
    }
  }
  float bv = bo[o];
#pragma unroll
  for (int j = 0; j < 16; ++j) {
    int l = l0 + j;
    if (l < L_) y[((size_t)b * L_ + l) * D_ + o] = acc[j] + bv;
  }
}

// ---------------- codebook prep
__global__ __launch_bounds__(64) void cbprep_k(const float* __restrict__ cb,
                                               float* __restrict__ cbT,
                                               float* __restrict__ cnorm)
{
  const int n = blockIdx.x, t = threadIdx.x;
  float s = 0.f;
  for (int d = t; d < D_; d += 64) {
    float vv = cb[(size_t)n * D_ + d];
    cbT[(size_t)d * NC_ + n] = vv;
    s += vv * vv;
  }
#pragma unroll
  for (int off = 32; off >= 1; off >>= 1) s += __shfl_xor(s, off);
  if (t == 0) cnorm[n] = s;
}

// ---------------- VQ distance GEMM + partial argmin.
// A-stage reads yattn [b][l][d] directly (coalesced: 32 consecutive d's per
// 32 lanes) -- itranspose kernel deleted.
__global__ __launch_bounds__(256, 2) void vqgemm_k(
    const float* __restrict__ yattn, const float* __restrict__ cbT,
    const float* __restrict__ cnorm, float* __restrict__ pmin, int* __restrict__ pidx)
{
  const int b = blockIdx.y, nt = blockIdx.x;
  const int tid = threadIdx.x;
  const int w = tid >> 6, lane = tid & 63;
  const int lrow = lane >> 3, ncol = lane & 7;
  __shared__ __align__(16) float As[32 * 68];
  __shared__ __align__(16) float Bs[32 * 256];
  __shared__ float redv[4][64];
  __shared__ int   redi[4][64];
  float acc[8][8];
#pragma unroll
  for (int li = 0; li < 8; ++li)
#pragma unroll
    for (int nj = 0; nj < 8; ++nj) acc[li][nj] = 0.f;

  const float* yb = yattn + (size_t)b * L_ * D_;
  const int n0 = nt * 256;
  const int nbase = n0 + w * 64 + ncol * 8;

  for (int d0 = 0; d0 < D_; d0 += 32) {
    __syncthreads();
#pragma unroll
    for (int i = 0; i < 8; ++i) {
      int e = tid + i * 256;
      int l = e >> 5, dd = e & 31;     // consecutive tid -> consecutive d
      As[dd * 68 + l] = (l < L_) ? yb[(size_t)l * D_ + d0 + dd] : 0.f;
    }
#pragma unroll
    for (int i = 0; i < 8; ++i) {
      int e = tid + i * 256;
      int dd = e >> 6, n4 = (e & 63) * 4;
      *reinterpret_cast<float4*>(&Bs[dd * 256 + n4]) =
          *reinterpret_cast<const float4*>(&cbT[(size_t)(d0 + dd) * NC_ + n0 + n4]);
    }
    __syncthreads();
#pragma unroll 4
    for (int dd = 0; dd < 32; ++dd) {
      float a8[8], b8[8];
      *reinterpret_cast<float4*>(&a8[0]) = *reinterpret_cast<const float4*>(&As[dd * 68 + lrow * 8]);
      *reinterpret_cast<float4*>(&a8[4]) = *reinterpret_cast<const float4*>(&As[dd * 68 + lrow * 8 + 4]);
      *reinterpret_cast<float4*>(&b8[0]) = *reinterpret_cast<const float4*>(&Bs[dd * 256 + w * 64 + ncol * 8]);
      *reinterpret_cast<float4*>(&b8[4]) = *reinterpret_cast<const float4*>(&Bs[dd * 256 + w * 64 + ncol * 8 + 4]);
#pragma unroll
      for (int li = 0; li < 8; ++li)
#pragma unroll
        for (int nj = 0; nj < 8; ++nj)
          acc[li][nj] += a8[li] * b8[nj];
    }
  }

  float cn[8];
  *reinterpret_cast<float4*>(&cn[0]) = *reinterpret_cast<const float4*>(&cnorm[nbase]);
  *reinterpret_cast<float4*>(&cn[4]) = *reinterpret_cast<const float4*>(&cnorm[nbase + 4]);
#pragma unroll
  for (int li = 0; li < 8; ++li) {
    float vb = cn[0] - 2.f * acc[li][0];
    int ib = nbase;
#pragma unroll
    for (int nj = 1; nj < 8; ++nj) {
      float v = cn[nj] - 2.f * acc[li][nj];
      if (v < vb) { vb = v; ib = nbase + nj; }
    }
#pragma unroll
    for (int off = 1; off <= 4; off <<= 1) {
      float vo = __shfl_xor(vb, off);
      int io = __shfl_xor(ib, off);
      if (vo < vb || (vo == vb && io < ib)) { vb = vo; ib = io; }
    }
    if (ncol == 0) { redv[w][lrow * 8 + li] = vb; redi[w][lrow * 8 + li] = ib; }
  }
  __syncthreads();
  if (tid < L_) {
    float vb = redv[0][tid]; int ib = redi[0][tid];
#pragma unroll
    for (int w2 = 1; w2 < 4; ++w2) {
      float vo = redv[w2][tid]; int io = redi[w2][tid];
      if (vo < vb || (vo == vb && io < ib)) { vb = vo; ib = io; }
    }
    pmin[((size_t)b * L_ + tid) * 8 + nt] = vb;
    pidx[((size_t)b * L_ + tid) * 8 + nt] = ib;
  }
}

// ---------------- VQ final
__global__ __launch_bounds__(64) void vqfin_k(
    const float* __restrict__ y, const float* __restrict__ cbook,
    const float* __restrict__ pmin, const int* __restrict__ pidx,
    float* __restrict__ zq, float* __restrict__ oidx, float* __restrict__ lpart)
{
  const int bl = blockIdx.x;
  const int tid = threadIdx.x;
  __shared__ int sidx;
  if (tid == 0) {
    float vb = pmin[(size_t)bl * 8];
    int ib = pidx[(size_t)bl * 8];
    for (int ntv = 1; ntv < 8; ++ntv) {
      float vo = pmin[(size_t)bl * 8 + ntv];
      int io = pidx[(size_t)bl * 8 + ntv];
      if (vo < vb || (vo == vb && io < ib)) { vb = vo; ib = io; }
    }
    sidx = ib;
  }
  __syncthreads();
  const int idx = sidx;
  const float* crow = cbook + (size_t)idx * D_;
  const float* yrow = y + (size_t)bl * D_;
  float s = 0.f;
  for (int d = tid; d < D_; d += 64) {
    float c = crow[d];
    float df = c - yrow[d];
    zq[(size_t)bl * D_ + d] = c;
    s += df * df;
  }
#pragma unroll
  for (int off = 32; off >= 1; off >>= 1) s += __shfl_xor(s, off);
  if (tid == 0) { lpart[bl] = s; oidx[bl] = (float)idx; }
}

// ---------------- loss reduce
__global__ __launch_bounds__(256) void loss_k(const float* __restrict__ lpart,
                                              float* __restrict__ outLoss)
{
  const int tid = threadIdx.x;
  float s = 0.f;
  for (int i = tid; i < B_ * L_; i += 256) s += lpart[i];
  __shared__ float red[256];
  red[tid] = s;
  __syncthreads();
  for (int off = 128; off >= 1; off >>= 1) {
    if (tid < off) red[tid] += red[tid + off];
    __syncthreads();
  }
  if (tid == 0) outLoss[0] = red[0] * ((1.f + 0.2f) / (float)((size_t)B_ * L_ * D_));
}

extern "C" void kernel_launch(void* const* d_in, const int* in_sizes, int n_in,
                              void* d_out, int out_size, void* d_ws, size_t ws_size,
                              hipStream_t stream)
{
  const float* x  = (const float*)d_in[0];
  const float* w1 = (const float*)d_in[1];  const float* b1 = (const float*)d_in[2];
  const float* w2 = (const float*)d_in[3];  const float* b2 = (const float*)d_in[4];
  const float* w3 = (const float*)d_in[5];  const float* b3 = (const float*)d_in[6];
  const float* w4 = (const float*)d_in[7];  const float* b4 = (const float*)d_in[8];
  const float* w5 = (const float*)d_in[9];  const float* b5 = (const float*)d_in[10];
  const float* w6 = (const float*)d_in[11]; const float* b6 = (const float*)d_in[12];
  const float* wq = (const float*)d_in[13];
  const float* wk = (const float*)d_in[14];
  const float* wv = (const float*)d_in[15];
  const float* wo = (const float*)d_in[16];
  const float* bo = (const float*)d_in[17];
  const float* cbook = (const float*)d_in[18];

  float* ws = (float*)d_ws;
  // wT region (round-17 layout, unpadded wT1)
  float* wT1 = ws;                  // 67,200
  float* wT2 = ws + 67200;          // 24,576
  float* wT3 = ws + 91776;          // 98,304
  float* wT4 = ws + 190080;         // 393,216
  float* wT5 = ws + 583296;         // 524,288
  float* wT6 = ws + 1107584;        // 524,288 -> ends 1,631,872

  // Full-batch layout needs 18,507,840 floats (74.04 MB).
  const bool FULL = (ws_size >= (size_t)18507840 * 4);

  // conv weight re-layouts
  wtrans_k<<<(1050 * 64 + 255) / 256, 256, 0, stream>>>(w1, wT1, 1050, 64);
  wtrans_k<<<( 192 * 128 + 255) / 256, 256, 0, stream>>>(w2, wT2, 192, 128);
  wtrans_k<<<( 384 * 256 + 255) / 256, 256, 0, stream>>>(w3, wT3, 384, 256);
  wtrans_k<<<( 768 * 512 + 255) / 256, 256, 0, stream>>>(w4, wT4, 768, 512);
  wtrans_k<<<(1024 * 512 + 255) / 256, 256, 0, stream>>>(w5, wT5, 1024, 512);
  wtrans_k<<<(1024 * 512 + 255) / 256, 256, 0, stream>>>(w6, wT6, 1024, 512);

  float* c6;
  if (FULL) {
    // ---- Full-batch conv (round-17 proven config); conv1-5 TT=128 ----
    float* P = ws + 1640000;
    float* Q = ws + 9140032;
    c6 = ws + 16640064;
    conv1dw_k<105,10,3, 64,21><<<dim3(15,1,B_),256,0,stream>>>(x, wT1,b1, P, 5500,1831);
    conv1dw_k< 64, 3,2,128,32><<<dim3( 8,2,B_),256,0,stream>>>(P, wT2,b2, Q, 1831, 915);
    conv1dw_k<128, 3,2,256,32><<<dim3( 4,4,B_),256,0,stream>>>(Q, wT3,b3, P,  915, 457);
    conv1dw_k<256, 3,2,512,32><<<dim3( 2,8,B_),256,0,stream>>>(P, wT4,b4, Q,  457, 228);
    convksw_k<256,2,2,512,32,2><<<dim3(1,16,B_),256,0,stream>>>(
        Q, wT5, P, 228, 114, 512 * 228, 3735552);
    convks6f_k<<<dim3(1,32,B_),256,0,stream>>>(P, wT6, b5, Q, 3735552, 1867776);
    redbias_k<512,57,4><<<(1867776 + 255) / 256, 256, 0, stream>>>(
        Q, b6, c6, 1867776, 1867776);
  } else {
    // ---- Half-batch fallback (proven TT=64 path) ----
    float* bufA = ws + 1632000;
    float* bufB = ws + 5382016;
    c6 = ws + 9132032;
    for (int h = 0; h < 2; ++h) {
      const float* xh = x + (size_t)h * HB_ * 105 * 5500;
      float* c6h = c6 + (size_t)h * HB_ * D_ * L_;
      conv1d_k<105,10,3, 64,21><<<dim3(29,1,HB_),256,0,stream>>>(xh,   wT1,b1, bufA, 5500,1831);
      conv1d_k< 64, 3,2,128,32><<<dim3(15,2,HB_),256,0,stream>>>(bufA, wT2,b2, bufB, 1831, 915);
      conv1d_k<128, 3,2,256,32><<<dim3( 8,4,HB_),256,0,stream>>>(bufB, wT3,b3, bufA,  915, 457);
      conv1d_k<256, 3,2,512,32><<<dim3( 4,8,HB_),256,0,stream>>>(bufA, wT4,b4, bufB,  457, 228);
      convks_k<256,2,2,512,32,2><<<dim3(2,16,HB_),256,0,stream>>>(
          bufB, wT5, bufA, 228, 114, 512 * 228, 1867776);
      convks6f_k<<<dim3(1,32,HB_),256,0,stream>>>(
          bufA, wT6, b5, bufB, 1867776, 933888);
      redbias_k<512,57,4><<<(933888 + 255) / 256, 256, 0, stream>>>(
          bufB, b6, c6h, 933888, 933888);
    }
  }

  // post-conv regions (conv scratch dead)
  float* qb     = ws;               // 1,867,776
  float* kb     = ws + 1867776;
  float* vb     = ws + 3735552;     // ends 5,603,328
  float* wqkvT  = ws + 5603328;     // 786,432
  float* cat    = ws + 7471104;     // 1,867,776
  float* yattn  = ws;               // (qb dead after attn)
  float* cbT    = ws + 11206656;    // 1,048,576
  float* cnorm  = ws + 12255232;    // 2,048
  float* pminb  = ws + 12257280;    // 29,184
  int*   pidxb  = (int*)(ws + 12286464); // 29,184
  float* lpart  = ws + 12315648;    // 3,648

  float* zq      = (float*)d_out;
  float* outLoss = zq + (size_t)B_ * L_ * D_;
  float* outIdx  = outLoss + 1;

  // attention (QKV reads c6 directly in [d][l] layout)
  wqkvprep_k<<<(786432 + 255) / 256, 256, 0, stream>>>(wq, wk, wv, wqkvT);
  qkvgemm_k<<<dim3(6, B_), 256, 0, stream>>>(c6, wqkvT, qb, kb, vb);
  cbprep_k<<<NC_, 64, 0, stream>>>(cbook, cbT, cnorm);
  attn_k<<<B_ * H_, 256, 0, stream>>>(qb, kb, vb, cat);
  outproj_k<<<dim3(8, B_), 256, 0, stream>>>(cat, wo, bo, yattn);

  // VQ reads yattn directly (itranspose deleted)
  vqgemm_k<<<dim3(8, B_), 256, 0, stream>>>(yattn, cbT, cnorm, pminb, pidxb);
  vqfin_k<<<B_ * L_, 64, 0, stream>>>(yattn, cbook, pminb, pidxb, zq, outIdx, lpart);
  loss_k<<<1, 256, 0, stream>>>(lpart, outLoss);
}